// Round 9
// baseline (67.362 us; speedup 1.0000x reference)
//
#include <hip/hip_runtime.h>

// ============================ DIAGNOSTIC ROUND =============================
// gemm tile-pass repeated REPEAT times (esum scaled by 1/REPEAT in epilogue)
// to lift the gemm dispatch above the harness fillBuffer dispatches (40-45us)
// so its full rocprof counter row becomes visible, and so that
// (total - r8_total)/2 directly measures one gemm pass. Structure otherwise
// byte-identical to round 8.
// ===========================================================================
#define REPEAT   3

#define N_ROWS   1024
#define D_DIM    128
#define C_CLS    50000
#define C_PAD    50048
#define NCT64    782        // 50048/64 column tiles (64 cols each)
#define NG       96         // ct groups; 782 = 8*96 + 14
#define NPART    192        // partials per row = NG * 2 col-halves
#define S_SCALE  30.0f
#define M_MARGIN 0.35f
#define EXP2_SCALE 43.2808512266689f   // 30 * log2(e)

typedef short s8v __attribute__((ext_vector_type(8)));   // 8 x bf16 bits (4 VGPRs)
typedef float f4v __attribute__((ext_vector_type(4)));

__device__ inline unsigned short f2bf(float f) {
    unsigned u = __float_as_uint(f);
    u += 0x7FFF + ((u >> 16) & 1);      // round-to-nearest-even (inputs are finite)
    return (unsigned short)(u >> 16);
}
__device__ inline float bf2f(unsigned short h) {
    return __uint_as_float(((unsigned)h) << 16);
}
__device__ inline void load_lds16(const char* src, unsigned char* lds) {
    __builtin_amdgcn_global_load_lds(
        (const __attribute__((address_space(1))) void*)src,
        (__attribute__((address_space(3))) void*)lds, 16, 0, 0);
}

// ---------------------------------------------------------------------------
// Fused row-normalize: rows [0,C_PAD) = weight -> what (rows >= C_CLS zeroed),
// rows [C_PAD, C_PAD+N_ROWS) = feature -> fhat. One wave per row.
// ---------------------------------------------------------------------------
__global__ void norm_rows_fused(const float* __restrict__ weight,
                                const float* __restrict__ feature,
                                unsigned short* __restrict__ what,
                                unsigned short* __restrict__ fhat) {
    int wid = threadIdx.x >> 6, lane = threadIdx.x & 63;
    int r = blockIdx.x * 4 + wid;
    const float* src;
    unsigned short* dst;
    int srcRow, valid;
    if (r < C_PAD) {                      // wave-uniform branch
        src = weight; dst = what; srcRow = r; valid = (r < C_CLS);
    } else {
        src = feature; dst = fhat; srcRow = r - C_PAD; valid = 1;
    }
    float2 v = make_float2(0.f, 0.f);
    if (valid) v = ((const float2*)src)[(size_t)srcRow * 64 + lane];
    float ss = v.x * v.x + v.y * v.y;
    #pragma unroll
    for (int s = 1; s < 64; s <<= 1) ss += __shfl_xor(ss, s, 64);
    float inv = valid ? 1.0f / fmaxf(sqrtf(ss), 1e-8f) : 0.f;
    ((ushort2*)dst)[(size_t)srcRow * 64 + lane] =
        make_ushort2(f2bf(v.x * inv), f2bf(v.y * inv));
}

// ---------------------------------------------------------------------------
// ct-loop GEMM+exp (round-8 structure), tile-pass run REPEAT times.
// Block (g, rt): 128 rows x 64 cols per tile, tiles ct = g + 96*t.
// A (128x128 = 32KB) staged once through LDS into registers. B tiles
// (64 rows x 128 K = 16KB) cycle through THREE 16KB LDS buffers, staged
// 2-ahead with global_load_lds (XOR swizzle on the GLOBAL source, linear
// LDS dest, swizzled ds_read). Per tile: counted s_waitcnt vmcnt(4) ->
// one raw s_barrier -> issue stage(t+2) -> ds_read+MFMA+exp.
// Wave layout 2x2. Pass boundary: __syncthreads() so re-staging is safe.
// ---------------------------------------------------------------------------
__global__ __launch_bounds__(256, 3)
void gemm_exp_kernel(const short* __restrict__ fhat,
                     const short* __restrict__ what,
                     float* __restrict__ part2) {
    __shared__ __align__(16) unsigned char smem[49152];   // 3 x 16KB B buffers
    const int g   = blockIdx.x;           // ct group, 0..95
    const int rt  = blockIdx.y;           // row tile, 0..7
    const int tid = threadIdx.x;
    const int wid = tid >> 6;
    const int lane = tid & 63;
    const int lrow = lane & 15;
    const int kgrp = lane >> 4;
    const int wrow = wid >> 1;            // row half (64 rows)
    const int wcol = wid & 1;             // col half (32 cols)
    const int nt = (g < 14) ? 9 : 8;      // tiles in this group (782 = 8*96+14)

    const char* aSrc  = (const char*)fhat + (size_t)rt * 32768;
    const char* bBase = (const char*)what;

    // ---- prologue: A tile (32KB) -> smem[0..32K), then A -> registers ----
    #pragma unroll
    for (int i = 0; i < 8; i++) {
        int o = wid * 8192 + i * 1024 + lane * 16;
        int s = o ^ (((o >> 8) & 7) << 4);      // source pre-swizzle (involution)
        load_lds16(aSrc + s, smem + o);
    }
    __syncthreads();

    s8v afr[4][4];                        // wave rows: wrow*64 + m*16 + lrow
    #pragma unroll
    for (int kk = 0; kk < 4; kk++)
        #pragma unroll
        for (int m = 0; m < 4; m++) {
            int row = wrow * 64 + m * 16 + lrow;
            int b = (row * 256 + kk * 64 + kgrp * 16) ^ ((row & 7) << 4);
            afr[kk][m] = *(const s8v*)(smem + b);
        }
    __syncthreads();                      // afr reads retired; smem reusable

    float esum[4][4];
    #pragma unroll
    for (int m = 0; m < 4; m++)
        #pragma unroll
        for (int j = 0; j < 4; j++) esum[m][j] = 0.f;

    for (int rep = 0; rep < REPEAT; ++rep) {
        // ---- stage B(t=0) -> buf0, B(t=1) -> buf1 (4 loads/wave each) ----
        #pragma unroll
        for (int i = 0; i < 4; i++) {
            int o = wid * 4096 + i * 1024 + lane * 16;
            int s = o ^ (((o >> 8) & 7) << 4);
            load_lds16(bBase + (size_t)g * 16384 + s, smem + o);
            load_lds16(bBase + (size_t)(g + 96) * 16384 + s, smem + 16384 + o);
        }

        for (int t = 0; t < nt; ++t) {
            const int ct = g + 96 * t;
            // counted wait: tile t's 4 loads done; t+1's 4 may stay in flight
            if (t + 1 < nt) asm volatile("s_waitcnt vmcnt(4)" ::: "memory");
            else            asm volatile("s_waitcnt vmcnt(0)" ::: "memory");
            __builtin_amdgcn_s_barrier();     // tile t fully in LDS
            __builtin_amdgcn_sched_barrier(0);

            if (t + 2 < nt) {                 // stage t+2 BEFORE compute (T3 order)
                const char* src = bBase + (size_t)(ct + 192) * 16384;
                unsigned char* dstb = smem + ((t + 2) % 3) * 16384;
                #pragma unroll
                for (int i = 0; i < 4; i++) {
                    int o = wid * 4096 + i * 1024 + lane * 16;
                    int s = o ^ (((o >> 8) & 7) << 4);
                    load_lds16(src + s, dstb + o);
                }
            }

            const unsigned char* bb = smem + (t % 3) * 16384;
            f4v acc[4][2];
            f4v zero = {0.f, 0.f, 0.f, 0.f};
            #pragma unroll
            for (int m = 0; m < 4; m++) { acc[m][0] = zero; acc[m][1] = zero; }

            #pragma unroll
            for (int kk = 0; kk < 4; kk++) {
                s8v bfr[2];
                #pragma unroll
                for (int n = 0; n < 2; n++) {
                    int row = wcol * 32 + n * 16 + lrow;   // B^T row = output col
                    int b = (row * 256 + kk * 64 + kgrp * 16) ^ ((row & 7) << 4);
                    bfr[n] = *(const s8v*)(bb + b);
                }
                #pragma unroll
                for (int m = 0; m < 4; m++) {
                    acc[m][0] = __builtin_amdgcn_mfma_f32_16x16x32_bf16(
                        afr[kk][m], bfr[0], acc[m][0], 0, 0, 0);
                    acc[m][1] = __builtin_amdgcn_mfma_f32_16x16x32_bf16(
                        afr[kk][m], bfr[1], acc[m][1], 0, 0, 0);
                }
            }

            if (ct != NCT64 - 1) {            // fast path: all 32 cols valid
                #pragma unroll
                for (int m = 0; m < 4; m++)
                    #pragma unroll
                    for (int n = 0; n < 2; n++)
                        #pragma unroll
                        for (int j = 0; j < 4; j++)
                            esum[m][j] += __builtin_amdgcn_exp2f(EXP2_SCALE * acc[m][n][j]);
            } else {                          // tail tile: mask padded cols
                #pragma unroll
                for (int n = 0; n < 2; n++) {
                    int gc = ct * 64 + wcol * 32 + n * 16 + lrow;
                    #pragma unroll
                    for (int m = 0; m < 4; m++)
                        #pragma unroll
                        for (int j = 0; j < 4; j++)
                            if (gc < C_CLS)
                                esum[m][j] += __builtin_amdgcn_exp2f(EXP2_SCALE * acc[m][n][j]);
                }
            }
        }
        __syncthreads();                  // pass boundary: all reads retired
    }

    // ---- epilogue: reduce over the wave's 16 col-lanes, direct write ----
    const float invrep = 1.0f / (float)REPEAT;
    #pragma unroll
    for (int m = 0; m < 4; m++)
        #pragma unroll
        for (int j = 0; j < 4; j++) {
            float v = esum[m][j] * invrep;
            v += __shfl_xor(v, 1, 64);
            v += __shfl_xor(v, 2, 64);
            v += __shfl_xor(v, 4, 64);
            v += __shfl_xor(v, 8, 64);
            if (lrow == 0) {
                int row = rt * 128 + wrow * 64 + m * 16 + kgrp * 4 + j;
                part2[(size_t)row * NPART + g * 2 + wcol] = v;
            }
        }
}

// ---------------------------------------------------------------------------
// One wave per row: S_n = sum of 192 partials (3 per lane); cos_y via fp32
// dot of the SAME bf16 normalized vectors; center loss on fp32 inputs.
// rowval[n] = (lse_n - t_n)/N + 0.005 * ||f_n - w_y||^2
// ---------------------------------------------------------------------------
__global__ void finalize_rows_kernel(const float* __restrict__ part2,
                                     const unsigned short* __restrict__ fhat,
                                     const unsigned short* __restrict__ what,
                                     const float* __restrict__ feature,
                                     const float* __restrict__ weight,
                                     const int* __restrict__ label,
                                     float* __restrict__ rowval) {
    int wid = threadIdx.x >> 6, lane = threadIdx.x & 63;
    int n = blockIdx.x * 4 + wid;
    int y = label[n];

    const float* p = part2 + (size_t)n * NPART;
    float S = p[lane] + p[64 + lane] + p[128 + lane];

    float2 f2 = ((const float2*)feature)[(size_t)n * 64 + lane];
    float2 w2 = ((const float2*)weight)[(size_t)y * 64 + lane];
    float dx = f2.x - w2.x, dy = f2.y - w2.y;
    float cl = dx * dx + dy * dy;

    ushort2 fh = ((const ushort2*)fhat)[(size_t)n * 64 + lane];
    ushort2 wh = ((const ushort2*)what)[(size_t)y * 64 + lane];
    float cy = bf2f(fh.x) * bf2f(wh.x) + bf2f(fh.y) * bf2f(wh.y);

    #pragma unroll
    for (int s = 1; s < 64; s <<= 1) {
        S  += __shfl_xor(S, s, 64);
        cl += __shfl_xor(cl, s, 64);
        cy += __shfl_xor(cy, s, 64);
    }
    if (lane == 0) {
        float t  = S_SCALE * (cy - M_MARGIN);
        float Sp = S - __expf(S_SCALE * cy) + __expf(t);
        rowval[n] = (logf(Sp) - t) * (1.0f / (float)N_ROWS) + 0.005f * cl;
    }
}

__global__ void reduce_final_kernel(const float* __restrict__ rowval, float* __restrict__ out) {
    __shared__ float sbuf[4];
    int t = threadIdx.x;
    float v = rowval[t] + rowval[t + 256] + rowval[t + 512] + rowval[t + 768];
    #pragma unroll
    for (int s = 1; s < 64; s <<= 1) v += __shfl_xor(v, s, 64);
    if ((t & 63) == 0) sbuf[t >> 6] = v;
    __syncthreads();
    if (t == 0) out[0] = sbuf[0] + sbuf[1] + sbuf[2] + sbuf[3];
}

// ---------------------------------------------------------------------------
extern "C" void kernel_launch(void* const* d_in, const int* in_sizes, int n_in,
                              void* d_out, int out_size, void* d_ws, size_t ws_size,
                              hipStream_t stream) {
    const float* feature = (const float*)d_in[0];
    const float* weight  = (const float*)d_in[1];
    const int*   label   = (const int*)d_in[2];

    // Workspace layout (bytes):
    //   what   [0,        12812288)  : 50048*128*2
    //   fhat   [12812288, 13074432)  : 1024*128*2
    //   part2  [13074432, 13860864)  : 1024*192*4
    //   rowval [13860864, 13864960)  : 1024*4
    const size_t WS_NEEDED = 13864960;
    if (ws_size < WS_NEEDED) return;   // defensive: visible failure, not OOB writes

    char* ws = (char*)d_ws;
    unsigned short* what = (unsigned short*)ws;
    unsigned short* fhat = (unsigned short*)(ws + 12812288);
    float*         part2 = (float*)(ws + 13074432);
    float*        rowval = (float*)(ws + 13860864);

    norm_rows_fused<<<dim3((C_PAD + N_ROWS) / 4), 256, 0, stream>>>(weight, feature, what, fhat);
    gemm_exp_kernel<<<dim3(NG, 8), 256, 0, stream>>>((const short*)fhat, (const short*)what, part2);
    finalize_rows_kernel<<<dim3(N_ROWS / 4), 256, 0, stream>>>(part2, fhat, what, feature, weight,
                                                               label, rowval);
    reduce_final_kernel<<<1, 256, 0, stream>>>(rowval, (float*)d_out);
}

// Round 10
// 63.957 us; speedup vs baseline: 1.0532x; 1.0532x over previous
//
#include <hip/hip_runtime.h>

#define N_ROWS   1024
#define D_DIM    128
#define C_CLS    50000
#define C_PAD    50048
#define NCT64    782        // 50048/64 column tiles (64 cols each)
#define NG       128        // ct groups; 782 = 6*128 + 14
#define NPART    256        // partials per row = NG * 2 col-halves
#define S_SCALE  30.0f
#define M_MARGIN 0.35f
#define EXP2_SCALE 43.2808512266689f    // 30 * log2(e)  (folded into fhat)
#define EXP2M      15.1482979293341f    // M_MARGIN * EXP2_SCALE
#define LN2        0.6931471805599453f

typedef short s8v __attribute__((ext_vector_type(8)));   // 8 x bf16 bits (4 VGPRs)
typedef float f4v __attribute__((ext_vector_type(4)));

__device__ inline unsigned short f2bf(float f) {
    unsigned u = __float_as_uint(f);
    u += 0x7FFF + ((u >> 16) & 1);      // round-to-nearest-even (inputs are finite)
    return (unsigned short)(u >> 16);
}
__device__ inline float bf2f(unsigned short h) {
    return __uint_as_float(((unsigned)h) << 16);
}
__device__ inline void load_lds16(const char* src, unsigned char* lds) {
    __builtin_amdgcn_global_load_lds(
        (const __attribute__((address_space(1))) void*)src,
        (__attribute__((address_space(3))) void*)lds, 16, 0, 0);
}

// ---------------------------------------------------------------------------
// Row-normalize, float4 (16B/lane), 2 rows per wave (half-wave per row).
// rows [0,C_PAD): weight -> what, unit norm (rows >= C_CLS zeroed).
// rows [C_PAD,+N_ROWS): feature -> fhat, norm SCALED by EXP2_SCALE so the
// GEMM's MFMA output is directly in exp2 units (kills the per-element v_mul).
// C_PAD % 8 == 0 -> every block/wave is type-uniform.
// ---------------------------------------------------------------------------
__global__ void norm_rows_fused(const float* __restrict__ weight,
                                const float* __restrict__ feature,
                                unsigned short* __restrict__ what,
                                unsigned short* __restrict__ fhat) {
    int wid = threadIdx.x >> 6, lane = threadIdx.x & 63;
    int half = lane >> 5, l32 = lane & 31;
    int r = blockIdx.x * 8 + wid * 2 + half;

    const float* src;
    unsigned short* dst;
    int srcRow, valid;
    float scale;
    if (r < C_PAD) {
        src = weight; dst = what; srcRow = r; valid = (r < C_CLS); scale = 1.0f;
    } else {
        src = feature; dst = fhat; srcRow = r - C_PAD; valid = 1; scale = EXP2_SCALE;
    }
    float4 v = make_float4(0.f, 0.f, 0.f, 0.f);
    if (valid) v = ((const float4*)src)[(size_t)srcRow * 32 + l32];
    float ss = v.x * v.x + v.y * v.y + v.z * v.z + v.w * v.w;
    #pragma unroll
    for (int s = 1; s < 32; s <<= 1) ss += __shfl_xor(ss, s, 32);
    float inv = valid ? scale / fmaxf(sqrtf(ss), 1e-8f) : 0.f;
    ushort4 o;
    o.x = f2bf(v.x * inv); o.y = f2bf(v.y * inv);
    o.z = f2bf(v.z * inv); o.w = f2bf(v.w * inv);
    ((ushort4*)dst)[(size_t)srcRow * 32 + l32] = o;
}

// ---------------------------------------------------------------------------
// ct-loop GEMM+exp, occupancy-first. Block (g, rt): 128 rows x 64 cols per
// tile, tiles ct = g + 128*t (6-7 tiles). LDS = 32KB total: A (32KB) bounces
// through it in the prologue -> registers; then it becomes TWO 16KB B
// buffers. Per tile: __syncthreads() (vmcnt0+lgkmcnt0+barrier = exactly the
// 1-deep-pipe semantic) -> issue stage(t+1) -> compute tile t. The stage
// latency hides under the full compute phase. XOR swizzle on the GLOBAL
// source (rule #21), linear LDS dest, swizzled ds_read. Wave layout 2x2.
// acc is already exp2-scaled (fhat folded) -> esum += exp2(acc) directly.
// 1024 blocks = exactly 4/CU (16 waves/CU) -> stalled blocks hidden by 3
// others. Grid linear id = g + 128*rt, 128 % 8 == 0 -> B-sharers on one XCD.
// ---------------------------------------------------------------------------
__global__ __launch_bounds__(256, 4)
void gemm_exp_kernel(const short* __restrict__ fhat,
                     const short* __restrict__ what,
                     float* __restrict__ part2) {
    __shared__ __align__(16) unsigned char smem[32768];   // 2 x 16KB B buffers
    const int g   = blockIdx.x;           // ct group, 0..127
    const int rt  = blockIdx.y;           // row tile, 0..7
    const int tid = threadIdx.x;
    const int wid = tid >> 6;
    const int lane = tid & 63;
    const int lrow = lane & 15;
    const int kgrp = lane >> 4;
    const int wrow = wid >> 1;            // row half (64 rows)
    const int wcol = wid & 1;             // col half (32 cols)
    const int nt = (g < 14) ? 7 : 6;      // tiles in this group (782 = 6*128+14)

    const char* aSrc  = (const char*)fhat + (size_t)rt * 32768;
    const char* bBase = (const char*)what;

    // ---- prologue: A tile (32KB) -> whole smem, then A -> registers ----
    #pragma unroll
    for (int i = 0; i < 8; i++) {
        int o = wid * 8192 + i * 1024 + lane * 16;
        int s = o ^ (((o >> 8) & 7) << 4);      // source pre-swizzle (involution)
        load_lds16(aSrc + s, smem + o);
    }
    __syncthreads();

    s8v afr[4][4];                        // wave rows: wrow*64 + m*16 + lrow
    #pragma unroll
    for (int kk = 0; kk < 4; kk++)
        #pragma unroll
        for (int m = 0; m < 4; m++) {
            int row = wrow * 64 + m * 16 + lrow;
            int b = (row * 256 + kk * 64 + kgrp * 16) ^ ((row & 7) << 4);
            afr[kk][m] = *(const s8v*)(smem + b);
        }
    __syncthreads();                      // afr reads retired; smem reusable

    // ---- stage B(t=0) -> buf0 ----
    #pragma unroll
    for (int i = 0; i < 4; i++) {
        int o = wid * 4096 + i * 1024 + lane * 16;
        int s = o ^ (((o >> 8) & 7) << 4);
        load_lds16(bBase + (size_t)g * 16384 + s, smem + o);
    }

    float esum[4][4];
    #pragma unroll
    for (int m = 0; m < 4; m++)
        #pragma unroll
        for (int j = 0; j < 4; j++) esum[m][j] = 0.f;

    for (int t = 0; t < nt; ++t) {
        const int ct = g + 128 * t;
        // vmcnt(0)+lgkmcnt(0)+barrier: stage(t) landed; buf[(t+1)&1]'s
        // readers (tile t-1) all done -> safe to overwrite.
        __syncthreads();

        if (t + 1 < nt) {                 // issue stage(t+1) BEFORE compute
            const char* src = bBase + (size_t)(ct + 128) * 16384;
            unsigned char* dstb = smem + ((t + 1) & 1) * 16384;
            #pragma unroll
            for (int i = 0; i < 4; i++) {
                int o = wid * 4096 + i * 1024 + lane * 16;
                int s = o ^ (((o >> 8) & 7) << 4);
                load_lds16(src + s, dstb + o);
            }
        }

        const unsigned char* bb = smem + (t & 1) * 16384;
        f4v acc[4][2];
        f4v zero = {0.f, 0.f, 0.f, 0.f};
        #pragma unroll
        for (int m = 0; m < 4; m++) { acc[m][0] = zero; acc[m][1] = zero; }

        #pragma unroll
        for (int kk = 0; kk < 4; kk++) {
            s8v bfr[2];
            #pragma unroll
            for (int n = 0; n < 2; n++) {
                int row = wcol * 32 + n * 16 + lrow;   // B^T row = output col
                int b = (row * 256 + kk * 64 + kgrp * 16) ^ ((row & 7) << 4);
                bfr[n] = *(const s8v*)(bb + b);
            }
            #pragma unroll
            for (int m = 0; m < 4; m++) {
                acc[m][0] = __builtin_amdgcn_mfma_f32_16x16x32_bf16(
                    afr[kk][m], bfr[0], acc[m][0], 0, 0, 0);
                acc[m][1] = __builtin_amdgcn_mfma_f32_16x16x32_bf16(
                    afr[kk][m], bfr[1], acc[m][1], 0, 0, 0);
            }
        }

        if (ct != NCT64 - 1) {            // fast path: all 32 cols valid
            #pragma unroll
            for (int m = 0; m < 4; m++)
                #pragma unroll
                for (int n = 0; n < 2; n++)
                    #pragma unroll
                    for (int j = 0; j < 4; j++)
                        esum[m][j] += __builtin_amdgcn_exp2f(acc[m][n][j]);
        } else {                          // tail tile: mask padded cols
            #pragma unroll
            for (int n = 0; n < 2; n++) {
                int gc = ct * 64 + wcol * 32 + n * 16 + lrow;
                #pragma unroll
                for (int m = 0; m < 4; m++)
                    #pragma unroll
                    for (int j = 0; j < 4; j++)
                        if (gc < C_CLS)
                            esum[m][j] += __builtin_amdgcn_exp2f(acc[m][n][j]);
            }
        }
    }

    // ---- epilogue: reduce over the wave's 16 col-lanes, direct write ----
    #pragma unroll
    for (int m = 0; m < 4; m++)
        #pragma unroll
        for (int j = 0; j < 4; j++) {
            float v = esum[m][j];
            v += __shfl_xor(v, 1, 64);
            v += __shfl_xor(v, 2, 64);
            v += __shfl_xor(v, 4, 64);
            v += __shfl_xor(v, 8, 64);
            if (lrow == 0) {
                int row = rt * 128 + wrow * 64 + m * 16 + kgrp * 4 + j;
                part2[(size_t)row * NPART + g * 2 + wcol] = v;
            }
        }
}

// ---------------------------------------------------------------------------
// One wave per row: S_n = sum of 256 partials (4 per lane). cys = fp32 dot of
// the SAME bf16 vectors = EXP2_SCALE*cos_y (fhat carries the scale), so
// Sp = S - exp2(cys) + exp2(cys - EXP2M) and lse - t = ln(Sp) - LN2*t2.
// rowval[n] = (ln(Sp) - LN2*t2)/N + 0.005 * ||f_n - w_y||^2
// ---------------------------------------------------------------------------
__global__ void finalize_rows_kernel(const float* __restrict__ part2,
                                     const unsigned short* __restrict__ fhat,
                                     const unsigned short* __restrict__ what,
                                     const float* __restrict__ feature,
                                     const float* __restrict__ weight,
                                     const int* __restrict__ label,
                                     float* __restrict__ rowval) {
    int wid = threadIdx.x >> 6, lane = threadIdx.x & 63;
    int n = blockIdx.x * 4 + wid;
    int y = label[n];

    const float* p = part2 + (size_t)n * NPART;
    float S = p[lane] + p[64 + lane] + p[128 + lane] + p[192 + lane];

    float2 f2 = ((const float2*)feature)[(size_t)n * 64 + lane];
    float2 w2 = ((const float2*)weight)[(size_t)y * 64 + lane];
    float dx = f2.x - w2.x, dy = f2.y - w2.y;
    float cl = dx * dx + dy * dy;

    ushort2 fh = ((const ushort2*)fhat)[(size_t)n * 64 + lane];
    ushort2 wh = ((const ushort2*)what)[(size_t)y * 64 + lane];
    float cys = bf2f(fh.x) * bf2f(wh.x) + bf2f(fh.y) * bf2f(wh.y);

    #pragma unroll
    for (int s = 1; s < 64; s <<= 1) {
        S   += __shfl_xor(S, s, 64);
        cl  += __shfl_xor(cl, s, 64);
        cys += __shfl_xor(cys, s, 64);
    }
    if (lane == 0) {
        float t2 = cys - EXP2M;
        float Sp = S - __builtin_amdgcn_exp2f(cys) + __builtin_amdgcn_exp2f(t2);
        rowval[n] = (logf(Sp) - LN2 * t2) * (1.0f / (float)N_ROWS) + 0.005f * cl;
    }
}

__global__ void reduce_final_kernel(const float* __restrict__ rowval, float* __restrict__ out) {
    __shared__ float sbuf[4];
    int t = threadIdx.x;
    float v = rowval[t] + rowval[t + 256] + rowval[t + 512] + rowval[t + 768];
    #pragma unroll
    for (int s = 1; s < 64; s <<= 1) v += __shfl_xor(v, s, 64);
    if ((t & 63) == 0) sbuf[t >> 6] = v;
    __syncthreads();
    if (t == 0) out[0] = sbuf[0] + sbuf[1] + sbuf[2] + sbuf[3];
}

// ---------------------------------------------------------------------------
extern "C" void kernel_launch(void* const* d_in, const int* in_sizes, int n_in,
                              void* d_out, int out_size, void* d_ws, size_t ws_size,
                              hipStream_t stream) {
    const float* feature = (const float*)d_in[0];
    const float* weight  = (const float*)d_in[1];
    const int*   label   = (const int*)d_in[2];

    // Workspace layout (bytes):
    //   what   [0,        12812288)  : 50048*128*2
    //   fhat   [12812288, 13074432)  : 1024*128*2
    //   part2  [13074432, 14123008)  : 1024*256*4
    //   rowval [14123008, 14127104)  : 1024*4
    const size_t WS_NEEDED = 14127104;
    if (ws_size < WS_NEEDED) return;   // defensive: visible failure, not OOB writes

    char* ws = (char*)d_ws;
    unsigned short* what = (unsigned short*)ws;
    unsigned short* fhat = (unsigned short*)(ws + 12812288);
    float*         part2 = (float*)(ws + 13074432);
    float*        rowval = (float*)(ws + 14123008);

    norm_rows_fused<<<dim3((C_PAD + N_ROWS) / 8), 256, 0, stream>>>(weight, feature, what, fhat);
    gemm_exp_kernel<<<dim3(NG, 8), 256, 0, stream>>>((const short*)fhat, (const short*)what, part2);
    finalize_rows_kernel<<<dim3(N_ROWS / 4), 256, 0, stream>>>(part2, fhat, what, feature, weight,
                                                               label, rowval);
    reduce_final_kernel<<<1, 256, 0, stream>>>(rowval, (float*)d_out);
}

// Round 11
// 35.995 us; speedup vs baseline: 1.8714x; 1.7768x over previous
//
#include <hip/hip_runtime.h>

#define N_ROWS   1024
#define D_DIM    128
#define C_CLS    50000
#define C_PAD    50048
#define NCT64    782        // 50048/64 column tiles (64 cols each)
#define NG       128        // ct groups; 782 = 6*128 + 14
#define NPART    256        // partials per row = NG * 2 col-halves
#define S_SCALE  30.0f
#define M_MARGIN 0.35f
#define EXP2_SCALE 43.2808512266689f    // 30 * log2(e)  (folded into fhat)
#define EXP2M      15.1482979293341f    // M_MARGIN * EXP2_SCALE
#define LN2        0.6931471805599453f

typedef short s8v __attribute__((ext_vector_type(8)));   // 8 x bf16 bits (4 VGPRs)
typedef float f4v __attribute__((ext_vector_type(4)));

__device__ inline unsigned short f2bf(float f) {
    unsigned u = __float_as_uint(f);
    u += 0x7FFF + ((u >> 16) & 1);      // round-to-nearest-even (inputs are finite)
    return (unsigned short)(u >> 16);
}
__device__ inline float bf2f(unsigned short h) {
    return __uint_as_float(((unsigned)h) << 16);
}
__device__ inline void load_lds16(const char* src, unsigned char* lds) {
    __builtin_amdgcn_global_load_lds(
        (const __attribute__((address_space(1))) void*)src,
        (__attribute__((address_space(3))) void*)lds, 16, 0, 0);
}

// ---------------------------------------------------------------------------
// Row-normalize, float4 (16B/lane), 2 rows per wave (half-wave per row).
// rows [0,C_PAD): weight -> what, unit norm (rows >= C_CLS zeroed).
// rows [C_PAD,+N_ROWS): feature -> fhat, norm SCALED by EXP2_SCALE so the
// GEMM's MFMA output is directly in exp2 units (kills the per-element v_mul).
// C_PAD % 8 == 0 -> every block/wave is type-uniform.
// ---------------------------------------------------------------------------
__global__ void norm_rows_fused(const float* __restrict__ weight,
                                const float* __restrict__ feature,
                                unsigned short* __restrict__ what,
                                unsigned short* __restrict__ fhat) {
    int wid = threadIdx.x >> 6, lane = threadIdx.x & 63;
    int half = lane >> 5, l32 = lane & 31;
    int r = blockIdx.x * 8 + wid * 2 + half;

    const float* src;
    unsigned short* dst;
    int srcRow, valid;
    float scale;
    if (r < C_PAD) {
        src = weight; dst = what; srcRow = r; valid = (r < C_CLS); scale = 1.0f;
    } else {
        src = feature; dst = fhat; srcRow = r - C_PAD; valid = 1; scale = EXP2_SCALE;
    }
    float4 v = make_float4(0.f, 0.f, 0.f, 0.f);
    if (valid) v = ((const float4*)src)[(size_t)srcRow * 32 + l32];
    float ss = v.x * v.x + v.y * v.y + v.z * v.z + v.w * v.w;
    #pragma unroll
    for (int s = 1; s < 32; s <<= 1) ss += __shfl_xor(ss, s, 32);
    float inv = valid ? scale / fmaxf(sqrtf(ss), 1e-8f) : 0.f;
    ushort4 o;
    o.x = f2bf(v.x * inv); o.y = f2bf(v.y * inv);
    o.z = f2bf(v.z * inv); o.w = f2bf(v.w * inv);
    ((ushort4*)dst)[(size_t)srcRow * 32 + l32] = o;
}

// ---------------------------------------------------------------------------
// ct-loop GEMM+exp. Block (g, rt): 128 rows x 64 cols per tile, tiles
// ct = g + 128*t (6-7 tiles). LDS = 32KB: A (32KB) bounces through it in the
// prologue -> registers; then it becomes TWO 16KB B buffers. Per tile:
// __syncthreads() -> issue stage(t+1) -> compute tile t (stage latency hides
// under the compute phase). XOR swizzle on the GLOBAL source (rule #21),
// linear LDS dest, swizzled ds_read. Wave layout 2x2. acc already
// exp2-scaled (fhat folded) -> esum += exp2(acc) directly.
// __launch_bounds__(256,3): r10's (256,4) made the allocator squeeze to 64
// arch VGPRs and SPILL (WRITE_SIZE 45MB of scratch, MfmaUtil 8%). At
// (256,3) the kernel allocates ~84 VGPR spill-free; since 84 <= 128, HW
// still resides 4 waves/SIMD (4 blocks/CU; LDS 32KB allows 5) -- the
// intended occupancy WITHOUT spills.
// Grid linear id = g + 128*rt, 128 % 8 == 0 -> B-sharers on one XCD.
// ---------------------------------------------------------------------------
__global__ __launch_bounds__(256, 3)
void gemm_exp_kernel(const short* __restrict__ fhat,
                     const short* __restrict__ what,
                     float* __restrict__ part2) {
    __shared__ __align__(16) unsigned char smem[32768];   // 2 x 16KB B buffers
    const int g   = blockIdx.x;           // ct group, 0..127
    const int rt  = blockIdx.y;           // row tile, 0..7
    const int tid = threadIdx.x;
    const int wid = tid >> 6;
    const int lane = tid & 63;
    const int lrow = lane & 15;
    const int kgrp = lane >> 4;
    const int wrow = wid >> 1;            // row half (64 rows)
    const int wcol = wid & 1;             // col half (32 cols)
    const int nt = (g < 14) ? 7 : 6;      // tiles in this group (782 = 6*128+14)

    const char* aSrc  = (const char*)fhat + (size_t)rt * 32768;
    const char* bBase = (const char*)what;

    // ---- prologue: A tile (32KB) -> whole smem, then A -> registers ----
    #pragma unroll
    for (int i = 0; i < 8; i++) {
        int o = wid * 8192 + i * 1024 + lane * 16;
        int s = o ^ (((o >> 8) & 7) << 4);      // source pre-swizzle (involution)
        load_lds16(aSrc + s, smem + o);
    }
    __syncthreads();

    s8v afr[4][4];                        // wave rows: wrow*64 + m*16 + lrow
    #pragma unroll
    for (int kk = 0; kk < 4; kk++)
        #pragma unroll
        for (int m = 0; m < 4; m++) {
            int row = wrow * 64 + m * 16 + lrow;
            int b = (row * 256 + kk * 64 + kgrp * 16) ^ ((row & 7) << 4);
            afr[kk][m] = *(const s8v*)(smem + b);
        }
    __syncthreads();                      // afr reads retired; smem reusable

    // ---- stage B(t=0) -> buf0 ----
    #pragma unroll
    for (int i = 0; i < 4; i++) {
        int o = wid * 4096 + i * 1024 + lane * 16;
        int s = o ^ (((o >> 8) & 7) << 4);
        load_lds16(bBase + (size_t)g * 16384 + s, smem + o);
    }

    float esum[4][4];
    #pragma unroll
    for (int m = 0; m < 4; m++)
        #pragma unroll
        for (int j = 0; j < 4; j++) esum[m][j] = 0.f;

    for (int t = 0; t < nt; ++t) {
        const int ct = g + 128 * t;
        // vmcnt(0)+lgkmcnt(0)+barrier: stage(t) landed; buf[(t+1)&1]'s
        // readers (tile t-1) all done -> safe to overwrite.
        __syncthreads();

        if (t + 1 < nt) {                 // issue stage(t+1) BEFORE compute
            const char* src = bBase + (size_t)(ct + 128) * 16384;
            unsigned char* dstb = smem + ((t + 1) & 1) * 16384;
            #pragma unroll
            for (int i = 0; i < 4; i++) {
                int o = wid * 4096 + i * 1024 + lane * 16;
                int s = o ^ (((o >> 8) & 7) << 4);
                load_lds16(src + s, dstb + o);
            }
        }

        const unsigned char* bb = smem + (t & 1) * 16384;
        f4v acc[4][2];
        f4v zero = {0.f, 0.f, 0.f, 0.f};
        #pragma unroll
        for (int m = 0; m < 4; m++) { acc[m][0] = zero; acc[m][1] = zero; }

        #pragma unroll
        for (int kk = 0; kk < 4; kk++) {
            s8v bfr[2];
            #pragma unroll
            for (int n = 0; n < 2; n++) {
                int row = wcol * 32 + n * 16 + lrow;   // B^T row = output col
                int b = (row * 256 + kk * 64 + kgrp * 16) ^ ((row & 7) << 4);
                bfr[n] = *(const s8v*)(bb + b);
            }
            #pragma unroll
            for (int m = 0; m < 4; m++) {
                acc[m][0] = __builtin_amdgcn_mfma_f32_16x16x32_bf16(
                    afr[kk][m], bfr[0], acc[m][0], 0, 0, 0);
                acc[m][1] = __builtin_amdgcn_mfma_f32_16x16x32_bf16(
                    afr[kk][m], bfr[1], acc[m][1], 0, 0, 0);
            }
        }

        if (ct != NCT64 - 1) {            // fast path: all 32 cols valid
            #pragma unroll
            for (int m = 0; m < 4; m++)
                #pragma unroll
                for (int n = 0; n < 2; n++)
                    #pragma unroll
                    for (int j = 0; j < 4; j++)
                        esum[m][j] += __builtin_amdgcn_exp2f(acc[m][n][j]);
        } else {                          // tail tile: mask padded cols
            #pragma unroll
            for (int n = 0; n < 2; n++) {
                int gc = ct * 64 + wcol * 32 + n * 16 + lrow;
                #pragma unroll
                for (int m = 0; m < 4; m++)
                    #pragma unroll
                    for (int j = 0; j < 4; j++)
                        if (gc < C_CLS)
                            esum[m][j] += __builtin_amdgcn_exp2f(acc[m][n][j]);
            }
        }
    }

    // ---- epilogue: reduce over the wave's 16 col-lanes, direct write ----
    #pragma unroll
    for (int m = 0; m < 4; m++)
        #pragma unroll
        for (int j = 0; j < 4; j++) {
            float v = esum[m][j];
            v += __shfl_xor(v, 1, 64);
            v += __shfl_xor(v, 2, 64);
            v += __shfl_xor(v, 4, 64);
            v += __shfl_xor(v, 8, 64);
            if (lrow == 0) {
                int row = rt * 128 + wrow * 64 + m * 16 + kgrp * 4 + j;
                part2[(size_t)row * NPART + g * 2 + wcol] = v;
            }
        }
}

// ---------------------------------------------------------------------------
// One wave per row: S_n = sum of 256 partials (4 per lane). cys = fp32 dot of
// the SAME bf16 vectors = EXP2_SCALE*cos_y (fhat carries the scale), so
// Sp = S - exp2(cys) + exp2(cys - EXP2M) and lse - t = ln(Sp) - LN2*t2.
// rowval[n] = (ln(Sp) - LN2*t2)/N + 0.005 * ||f_n - w_y||^2
// ---------------------------------------------------------------------------
__global__ void finalize_rows_kernel(const float* __restrict__ part2,
                                     const unsigned short* __restrict__ fhat,
                                     const unsigned short* __restrict__ what,
                                     const float* __restrict__ feature,
                                     const float* __restrict__ weight,
                                     const int* __restrict__ label,
                                     float* __restrict__ rowval) {
    int wid = threadIdx.x >> 6, lane = threadIdx.x & 63;
    int n = blockIdx.x * 4 + wid;
    int y = label[n];

    const float* p = part2 + (size_t)n * NPART;
    float S = p[lane] + p[64 + lane] + p[128 + lane] + p[192 + lane];

    float2 f2 = ((const float2*)feature)[(size_t)n * 64 + lane];
    float2 w2 = ((const float2*)weight)[(size_t)y * 64 + lane];
    float dx = f2.x - w2.x, dy = f2.y - w2.y;
    float cl = dx * dx + dy * dy;

    ushort2 fh = ((const ushort2*)fhat)[(size_t)n * 64 + lane];
    ushort2 wh = ((const ushort2*)what)[(size_t)y * 64 + lane];
    float cys = bf2f(fh.x) * bf2f(wh.x) + bf2f(fh.y) * bf2f(wh.y);

    #pragma unroll
    for (int s = 1; s < 64; s <<= 1) {
        S   += __shfl_xor(S, s, 64);
        cl  += __shfl_xor(cl, s, 64);
        cys += __shfl_xor(cys, s, 64);
    }
    if (lane == 0) {
        float t2 = cys - EXP2M;
        float Sp = S - __builtin_amdgcn_exp2f(cys) + __builtin_amdgcn_exp2f(t2);
        rowval[n] = (logf(Sp) - LN2 * t2) * (1.0f / (float)N_ROWS) + 0.005f * cl;
    }
}

__global__ void reduce_final_kernel(const float* __restrict__ rowval, float* __restrict__ out) {
    __shared__ float sbuf[4];
    int t = threadIdx.x;
    float v = rowval[t] + rowval[t + 256] + rowval[t + 512] + rowval[t + 768];
    #pragma unroll
    for (int s = 1; s < 64; s <<= 1) v += __shfl_xor(v, s, 64);
    if ((t & 63) == 0) sbuf[t >> 6] = v;
    __syncthreads();
    if (t == 0) out[0] = sbuf[0] + sbuf[1] + sbuf[2] + sbuf[3];
}

// ---------------------------------------------------------------------------
extern "C" void kernel_launch(void* const* d_in, const int* in_sizes, int n_in,
                              void* d_out, int out_size, void* d_ws, size_t ws_size,
                              hipStream_t stream) {
    const float* feature = (const float*)d_in[0];
    const float* weight  = (const float*)d_in[1];
    const int*   label   = (const int*)d_in[2];

    // Workspace layout (bytes):
    //   what   [0,        12812288)  : 50048*128*2
    //   fhat   [12812288, 13074432)  : 1024*128*2
    //   part2  [13074432, 14123008)  : 1024*256*4
    //   rowval [14123008, 14127104)  : 1024*4
    const size_t WS_NEEDED = 14127104;
    if (ws_size < WS_NEEDED) return;   // defensive: visible failure, not OOB writes

    char* ws = (char*)d_ws;
    unsigned short* what = (unsigned short*)ws;
    unsigned short* fhat = (unsigned short*)(ws + 12812288);
    float*         part2 = (float*)(ws + 13074432);
    float*        rowval = (float*)(ws + 14123008);

    norm_rows_fused<<<dim3((C_PAD + N_ROWS) / 8), 256, 0, stream>>>(weight, feature, what, fhat);
    gemm_exp_kernel<<<dim3(NG, 8), 256, 0, stream>>>((const short*)fhat, (const short*)what, part2);
    finalize_rows_kernel<<<dim3(N_ROWS / 4), 256, 0, stream>>>(part2, fhat, what, feature, weight,
                                                               label, rowval);
    reduce_final_kernel<<<1, 256, 0, stream>>>(rowval, (float*)d_out);
}